// Round 2
// baseline (8295.562 us; speedup 1.0000x reference)
//
#include <hip/hip_runtime.h>
#include <hip/hip_bf16.h>
#include <cstddef>

#define HIDDEN 512
#define ATOM_FDIM 133
#define BOND_FDIM 14
#define FB_DIM 147   // ATOM_FDIM + BOND_FDIM
#define MAX_NB 6

typedef __hip_bfloat16 bf16;

__device__ __forceinline__ float b2f(bf16 x) { return __bfloat162float(x); }
__device__ __forceinline__ bf16  f2b(float x) { return __float2bfloat16(x); }

// ---------------------------------------------------------------------------
// Stage a 16 x 512 tile of W (f32 row-major [K][512]) into LDS.
// ---------------------------------------------------------------------------
__device__ __forceinline__ void stage_W(float* Bs, const float* __restrict__ W,
                                        int k0, int K, int t)
{
    #pragma unroll
    for (int i = 0; i < 8; i++) {
        int f  = i * 256 + t;
        int br = f >> 7;            // 0..15
        int c4 = (f & 127) << 2;    // 0..508
        float4 v = make_float4(0.f, 0.f, 0.f, 0.f);
        if (k0 + br < K)
            v = *reinterpret_cast<const float4*>(&W[(size_t)(k0 + br) * HIDDEN + c4]);
        *reinterpret_cast<float4*>(Bs + br * HIDDEN + c4) = v;
    }
}

// ---------------------------------------------------------------------------
// FMA one 16-k tile: As [16][32] (k-major), Bs [16][512].
// ---------------------------------------------------------------------------
__device__ __forceinline__ void compute_tile(const float* As, const float* Bs,
                                             float acc[4][16], int rowg, int colg)
{
    #pragma unroll
    for (int k = 0; k < 16; k++) {
        float4 a = *reinterpret_cast<const float4*>(As + k * 32 + (rowg << 2));
        float b[16];
        #pragma unroll
        for (int ci = 0; ci < 16; ci++) b[ci] = Bs[k * HIDDEN + colg + (ci << 5)];
        #pragma unroll
        for (int r = 0; r < 4; r++) {
            float av = (&a.x)[r];
            #pragma unroll
            for (int ci = 0; ci < 16; ci++) acc[r][ci] = fmaf(av, b[ci], acc[r][ci]);
        }
    }
}

// ---------------------------------------------------------------------------
// Multi-phase tall GEMM, 32 rows/block, 256 threads, 4x16 acc/thread.
// Phases (each optional, skip when null):
//   P0: A = sum_j msg[a2a[row][j]]  (bf16, K=512) x Wm
//   P1: A = atomf[row]              (f32, lda=133, K=133) x Wa
//   P2: A = sum_j f_bonds[a2b[row][j]][133:147] (f32, K=14) x Wb
// Epilogue:
//   EPI 0: outv = relu(acc); if baseOut: baseOut = bf16(acc + float(baseOut))
//   EPI 1: outv = relu(acc + float(base))
//   EPI 2: outv = relu(acc + bias[col])
// ---------------------------------------------------------------------------
template<int EPI>
__global__ __launch_bounds__(256) void mp_gemm(
    const bf16*  __restrict__ msg,
    const int*   __restrict__ a2a,
    const float* __restrict__ Wm,
    const float* __restrict__ atomf,
    const float* __restrict__ Wa,
    const float* __restrict__ fbonds,
    const int*   __restrict__ a2b,
    const float* __restrict__ Wb,
    const bf16*  __restrict__ base,
    const float* __restrict__ bias,
    bf16* __restrict__ outv,
    bf16* __restrict__ baseOut,
    int M)
{
    __shared__ float Bs[16 * HIDDEN];   // 32 KB
    __shared__ float As[16 * 32];       // 2 KB
    __shared__ int   sIdxA[32][MAX_NB];
    __shared__ int   sIdxB[32][MAX_NB];

    const int t    = threadIdx.x;
    const int row0 = blockIdx.x * 32;
    const int colg = t & 31;
    const int rowg = t >> 5;

    if (t < 32 * MAX_NB) {
        int ar = t / MAX_NB, j = t % MAX_NB;
        int row = row0 + ar; if (row >= M) row = M - 1;
        if (msg)    sIdxA[ar][j] = a2a[(size_t)row * MAX_NB + j];
        if (fbonds) sIdxB[ar][j] = a2b[(size_t)row * MAX_NB + j];
    }

    float acc[4][16];
    #pragma unroll
    for (int r = 0; r < 4; r++)
        #pragma unroll
        for (int ci = 0; ci < 16; ci++) acc[r][ci] = 0.f;

    // ---- Phase 0: gathered message (bf16), K = 512 ----
    if (msg) {
        for (int k0 = 0; k0 < HIDDEN; k0 += 16) {
            __syncthreads();
            stage_W(Bs, Wm, k0, HIDDEN, t);
            #pragma unroll
            for (int i = 0; i < 2; i++) {
                int e = t * 2 + i, ar = e >> 4, kk = e & 15;
                float v = 0.f;
                #pragma unroll
                for (int j = 0; j < MAX_NB; j++)
                    v += b2f(msg[(size_t)sIdxA[ar][j] * HIDDEN + k0 + kk]);
                As[kk * 32 + ar] = v;
            }
            __syncthreads();
            compute_tile(As, Bs, acc, rowg, colg);
        }
    }
    // ---- Phase 1: direct atom features (f32), K = 133 ----
    if (atomf) {
        for (int k0 = 0; k0 < ATOM_FDIM; k0 += 16) {
            __syncthreads();
            stage_W(Bs, Wa, k0, ATOM_FDIM, t);
            #pragma unroll
            for (int i = 0; i < 2; i++) {
                int e = t * 2 + i, ar = e >> 4, kk = e & 15;
                int grow = row0 + ar;
                float v = 0.f;
                if (k0 + kk < ATOM_FDIM && grow < M)
                    v = atomf[(size_t)grow * ATOM_FDIM + k0 + kk];
                As[kk * 32 + ar] = v;
            }
            __syncthreads();
            compute_tile(As, Bs, acc, rowg, colg);
        }
    }
    // ---- Phase 2: gathered bond features (f32), K = 14 ----
    if (fbonds) {
        __syncthreads();
        stage_W(Bs, Wb, 0, BOND_FDIM, t);
        #pragma unroll
        for (int i = 0; i < 2; i++) {
            int e = t * 2 + i, ar = e >> 4, kk = e & 15;
            float v = 0.f;
            if (kk < BOND_FDIM) {
                #pragma unroll
                for (int j = 0; j < MAX_NB; j++)
                    v += fbonds[(size_t)sIdxB[ar][j] * FB_DIM + ATOM_FDIM + kk];
            }
            As[kk * 32 + ar] = v;
        }
        __syncthreads();
        compute_tile(As, Bs, acc, rowg, colg);
    }

    // ---- epilogue ----
    #pragma unroll
    for (int r = 0; r < 4; r++) {
        int row = row0 + (rowg << 2) + r;
        if (row >= M) continue;
        size_t rb = (size_t)row * HIDDEN;
        #pragma unroll
        for (int ci = 0; ci < 16; ci++) {
            int col = colg + (ci << 5);
            size_t idx = rb + col;
            float v = acc[r][ci];
            if (EPI == 0) {
                outv[idx] = f2b(fmaxf(v, 0.f));
                if (baseOut) baseOut[idx] = f2b(v + b2f(baseOut[idx]));
            } else if (EPI == 1) {
                outv[idx] = f2b(fmaxf(v + b2f(base[idx]), 0.f));
            } else {
                outv[idx] = f2b(fmaxf(v + bias[col], 0.f));
            }
        }
    }
}

// ---------------------------------------------------------------------------
// flags[i] = (sum of atom_features row i) > 0 ? 1 : 0.  One wave per row.
// ---------------------------------------------------------------------------
__global__ __launch_bounds__(256) void flags_k(const float* __restrict__ af,
                                               float* __restrict__ flags, int M)
{
    int w    = (blockIdx.x * 256 + threadIdx.x) >> 6;
    int lane = threadIdx.x & 63;
    if (w >= M) return;
    const float* row = af + (size_t)w * ATOM_FDIM;
    float s = 0.f;
    for (int c = lane; c < ATOM_FDIM; c += 64) s += row[c];
    #pragma unroll
    for (int off = 32; off; off >>= 1) s += __shfl_down(s, off);
    if (lane == 0) flags[w] = (s > 0.f) ? 1.f : 0.f;
}

// ---------------------------------------------------------------------------
// c_b[i] = (sum_j f_bonds[a2b[i][j]][133:147]) @ W_h[512:526] -> bf16
// ---------------------------------------------------------------------------
__global__ __launch_bounds__(256) void cb_k(const float* __restrict__ f_bonds,
                                            const int*   __restrict__ a2b,
                                            const float* __restrict__ Wh2,
                                            bf16* __restrict__ cb, int M)
{
    int atom = blockIdx.x * 4 + (threadIdx.x >> 6);
    int lane = threadIdx.x & 63;
    if (atom >= M) return;
    int bidx = (lane < MAX_NB) ? a2b[(size_t)atom * MAX_NB + lane] : 0;
    float nb = 0.f;
    if (lane < BOND_FDIM) {
        #pragma unroll
        for (int j = 0; j < MAX_NB; j++) {
            int b = __shfl(bidx, j);
            nb += f_bonds[(size_t)b * FB_DIM + ATOM_FDIM + lane];
        }
    }
    float acc[8];
    #pragma unroll
    for (int ci = 0; ci < 8; ci++) acc[ci] = 0.f;
    #pragma unroll
    for (int k = 0; k < BOND_FDIM; k++) {
        float nbk = __shfl(nb, k);
        #pragma unroll
        for (int ci = 0; ci < 8; ci++)
            acc[ci] += nbk * Wh2[(size_t)k * HIDDEN + lane + (ci << 6)];
    }
    size_t rb = (size_t)atom * HIDDEN;
    #pragma unroll
    for (int ci = 0; ci < 8; ci++) cb[rb + lane + (ci << 6)] = f2b(acc[ci]);
}

// ---------------------------------------------------------------------------
// Per-molecule segment mean + counts; mol_ids sorted -> binary search bounds.
// ---------------------------------------------------------------------------
__global__ __launch_bounds__(512) void seg_k(const bf16* __restrict__ hid,
                                             const float* __restrict__ flags,
                                             const int*   __restrict__ mol_ids,
                                             float* __restrict__ out, int M, int NM)
{
    int m = blockIdx.x;
    int t = threadIdx.x;
    int lo = 0, hi = M;
    while (lo < hi) { int mid = (lo + hi) >> 1; if (mol_ids[mid] < m) lo = mid + 1; else hi = mid; }
    int s = lo;
    lo = 0; hi = M;
    while (lo < hi) { int mid = (lo + hi) >> 1; if (mol_ids[mid] < m + 1) lo = mid + 1; else hi = mid; }
    int e = lo;

    float acc = 0.f;
    for (int a = s; a < e; a++) acc += b2f(hid[(size_t)a * HIDDEN + t]);
    float nzp = 0.f;
    for (int a = s + t; a < e; a += 512) nzp += flags[a];
    __shared__ float red[512];
    red[t] = nzp; __syncthreads();
    for (int off = 256; off; off >>= 1) { if (t < off) red[t] += red[t + off]; __syncthreads(); }

    int cnt = e - s;
    float inv = 1.f / fmaxf((float)cnt, 1.f);
    out[(size_t)m * HIDDEN + t] = acc * inv;
    if (t == 0) {
        out[(size_t)NM * HIDDEN + 2 * m]     = red[0];
        out[(size_t)NM * HIDDEN + 2 * m + 1] = (float)cnt;
    }
}

// ---------------------------------------------------------------------------
extern "C" void kernel_launch(void* const* d_in, const int* in_sizes, int n_in,
                              void* d_out, int out_size, void* d_ws, size_t ws_size,
                              hipStream_t stream)
{
    const float* atomf   = (const float*)d_in[0];
    const float* f_bonds = (const float*)d_in[1];
    const int*   a2a     = (const int*)d_in[2];
    const int*   a2b     = (const int*)d_in[3];
    const int*   mol_ids = (const int*)d_in[4];
    const float* W_i     = (const float*)d_in[5];
    const float* W_h     = (const float*)d_in[6];
    const float* W_o     = (const float*)d_in[7];
    const float* b_o     = (const float*)d_in[8];
    float* out = (float*)d_out;

    const int M  = in_sizes[2] / MAX_NB;   // 100000
    const int NM = 1000;
    const size_t SZ  = (size_t)M * HIDDEN;
    const size_t SZb = SZ * sizeof(bf16);  // 102.4 MB

    const float* Wh1 = W_h;                               // [512][512]
    const float* Wh2 = W_h + (size_t)HIDDEN * HIDDEN;     // [14][512]
    const float* Wo1 = W_o;                               // [133][512]
    const float* Wo2 = W_o + (size_t)ATOM_FDIM * HIDDEN;  // [512][512]

    const size_t need3 = 3 * SZb + (size_t)M * sizeof(float);
    const bool path3 = (ws_size >= need3);

    char* p = (char*)d_ws;
    bf16* baseB = nullptr;
    bf16 *msgA, *msgB;
    float* flags;
    if (path3) {
        baseB = (bf16*)p;           p += SZb;
        msgA  = (bf16*)p;           p += SZb;
        msgB  = (bf16*)p;           p += SZb;
        flags = (float*)p;
    } else {
        msgA  = (bf16*)p;           p += SZb;
        msgB  = (bf16*)p;           p += SZb;
        flags = (float*)p;
    }

    const int gA = (M + 3) / 4;
    const int gG = (M + 31) / 32;

    flags_k<<<gA, 256, 0, stream>>>(atomf, flags, M);

    if (path3) {
        // c_b -> baseB (bf16)
        cb_k<<<gA, 256, 0, stream>>>(f_bonds, a2b, Wh2, baseB, M);
        // msgA = relu(inp), baseB = bf16(inp + c_b)
        mp_gemm<0><<<gG, 256, 0, stream>>>(nullptr, nullptr, nullptr,
                                           atomf, W_i, nullptr, nullptr, nullptr,
                                           nullptr, nullptr, msgA, baseB, M);
        // 3 iters: msg' = relu(base + g6(msg) @ Wh1)
        mp_gemm<1><<<gG, 256, 0, stream>>>(msgA, a2a, Wh1, nullptr, nullptr,
                                           nullptr, nullptr, nullptr,
                                           baseB, nullptr, msgB, nullptr, M);
        mp_gemm<1><<<gG, 256, 0, stream>>>(msgB, a2a, Wh1, nullptr, nullptr,
                                           nullptr, nullptr, nullptr,
                                           baseB, nullptr, msgA, nullptr, M);
        mp_gemm<1><<<gG, 256, 0, stream>>>(msgA, a2a, Wh1, nullptr, nullptr,
                                           nullptr, nullptr, nullptr,
                                           baseB, nullptr, msgB, nullptr, M);
    } else {
        // msgA = relu(atomf @ W_i)
        mp_gemm<0><<<gG, 256, 0, stream>>>(nullptr, nullptr, nullptr,
                                           atomf, W_i, nullptr, nullptr, nullptr,
                                           nullptr, nullptr, msgA, nullptr, M);
        // 3 iters: msg' = relu(g6(msg)@Wh1 + atomf@W_i + bond@Wh2)
        mp_gemm<0><<<gG, 256, 0, stream>>>(msgA, a2a, Wh1, atomf, W_i,
                                           f_bonds, a2b, Wh2,
                                           nullptr, nullptr, msgB, nullptr, M);
        mp_gemm<0><<<gG, 256, 0, stream>>>(msgB, a2a, Wh1, atomf, W_i,
                                           f_bonds, a2b, Wh2,
                                           nullptr, nullptr, msgA, nullptr, M);
        mp_gemm<0><<<gG, 256, 0, stream>>>(msgA, a2a, Wh1, atomf, W_i,
                                           f_bonds, a2b, Wh2,
                                           nullptr, nullptr, msgB, nullptr, M);
    }
    // hid = relu(g6(msgB)@Wo2 + atomf@Wo1 + b_o) -> msgA
    mp_gemm<2><<<gG, 256, 0, stream>>>(msgB, a2a, Wo2, atomf, Wo1,
                                       nullptr, nullptr, nullptr,
                                       nullptr, b_o, msgA, nullptr, M);
    // segment mean + counts
    seg_k<<<NM, 512, 0, stream>>>(msgA, flags, mol_ids, out, M, NM);
}

// Round 3
// 1535.202 us; speedup vs baseline: 5.4036x; 5.4036x over previous
//
#include <hip/hip_runtime.h>
#include <hip/hip_bf16.h>
#include <cstddef>

#define HIDDEN 512
#define ATOM_FDIM 133
#define BOND_FDIM 14
#define FB_DIM 147
#define MAX_NB 6
#define BM 64
#define LDSROW 40          // ushorts per LDS row (80 B: 64 B data + 16 B pad)
#define KA_PAD 160         // atom K padded to 5 tiles of 32

typedef __attribute__((ext_vector_type(8))) short s16x8;
typedef __attribute__((ext_vector_type(4))) float f32x4;

__device__ __forceinline__ float uf(unsigned short u) {
    return __uint_as_float(((unsigned)u) << 16);
}
__device__ __forceinline__ unsigned short fb(float f) {
    __hip_bfloat16 h = __float2bfloat16(f);
    return *reinterpret_cast<unsigned short*>(&h);
}

// ---------------------------------------------------------------------------
// One-time weight convert: f32 [Ksrc][512] -> bf16 tile-K-major:
// chunk c (16 B = 8 bf16): tile = c>>11, n = (c&2047)>>2, s = c&3,
// holds W[tile*32 + s*8 + e][n], zero-padded past Ksrc.
// ---------------------------------------------------------------------------
__global__ __launch_bounds__(256) void cvt_w(const float* __restrict__ src,
                                             unsigned short* __restrict__ dst,
                                             int Ksrc, int nchunks)
{
    int c = blockIdx.x * 256 + threadIdx.x;
    if (c >= nchunks) return;
    int tile = c >> 11, rem = c & 2047, n = rem >> 2, s = rem & 3;
    s16x8 o;
    #pragma unroll
    for (int e = 0; e < 8; e++) {
        int k = tile * 32 + s * 8 + e;
        float v = (k < Ksrc) ? src[(size_t)k * HIDDEN + n] : 0.f;
        o[e] = (short)fb(v);
    }
    reinterpret_cast<s16x8*>(dst)[c] = o;
}

// ---------------------------------------------------------------------------
// MFMA multi-phase GEMM. 256 thr = 4 waves, BM=64 x BN=512, BK=32.
// Wave wn covers cols [wn*128, wn*128+128): 4 M-frags x 8 N-frags.
// Phases: P0 msg-gather K=512 (Wm 16 tiles), P1 atomf K=160 (Wa 5 tiles),
//         P2 bond-gather K=32 (Wb 1 tile).
// EPI 0: out=relu(acc); if baseOut: baseOut = bf16(acc + baseOut)
// EPI 1: out=relu(acc + base)
// EPI 2: out=relu(acc + bias[col])
// ---------------------------------------------------------------------------
template<int EPI, bool P0, bool P1, bool P2>
__global__ __launch_bounds__(256, 2) void mfma_gemm(
    const unsigned short* __restrict__ msg, const int* __restrict__ a2a,
    const unsigned short* __restrict__ Wm,
    const float* __restrict__ atomf, const unsigned short* __restrict__ Wa,
    const float* __restrict__ fbonds, const int* __restrict__ a2b,
    const unsigned short* __restrict__ Wb,
    const unsigned short* __restrict__ base, const float* __restrict__ bias,
    unsigned short* __restrict__ outv, unsigned short* __restrict__ baseOut,
    int M)
{
    __shared__ unsigned short As[BM * LDSROW];       // 5 KB
    __shared__ unsigned short Bs[HIDDEN * LDSROW];   // 40 KB
    __shared__ int sIdxA[BM][MAX_NB];
    __shared__ int sIdxB[BM][MAX_NB];

    const int t    = threadIdx.x;
    const int m0   = blockIdx.x * BM;
    const int lane = t & 63;
    const int l15  = lane & 15, lhi = lane >> 4;
    const int wn   = t >> 6;
    const int r_st = t >> 2, s_st = t & 3;           // staging coords

    if (P0 || P2) {
        for (int e = t; e < BM * MAX_NB; e += 256) {
            int r = e / MAX_NB, j = e % MAX_NB;
            int row = m0 + r; if (row >= M) row = M - 1;
            if (P0) sIdxA[r][j] = a2a[(size_t)row * MAX_NB + j];
            if (P2) sIdxB[r][j] = a2b[(size_t)row * MAX_NB + j];
        }
    }

    f32x4 acc[4][8];
    #pragma unroll
    for (int mr = 0; mr < 4; mr++)
        #pragma unroll
        for (int nr = 0; nr < 8; nr++)
            acc[mr][nr] = (f32x4){0.f, 0.f, 0.f, 0.f};

    auto stageB = [&](const unsigned short* Wt, int tile) {
        const s16x8* src = reinterpret_cast<const s16x8*>(Wt + (size_t)tile * HIDDEN * 32);
        #pragma unroll
        for (int i = 0; i < 8; i++) {
            int c = t + i * 256;
            s16x8 v = src[c];
            int n = c >> 2, s2 = c & 3;
            *reinterpret_cast<s16x8*>(&Bs[n * LDSROW + s2 * 8]) = v;
        }
    };

    auto compute = [&]() {
        s16x8 af[4];
        #pragma unroll
        for (int mr = 0; mr < 4; mr++)
            af[mr] = *reinterpret_cast<const s16x8*>(&As[(mr * 16 + l15) * LDSROW + lhi * 8]);
        #pragma unroll
        for (int nr = 0; nr < 8; nr++) {
            s16x8 bf = *reinterpret_cast<const s16x8*>(&Bs[(wn * 128 + nr * 16 + l15) * LDSROW + lhi * 8]);
            #pragma unroll
            for (int mr = 0; mr < 4; mr++)
                acc[mr][nr] = __builtin_amdgcn_mfma_f32_16x16x32_bf16(af[mr], bf, acc[mr][nr], 0, 0, 0);
        }
    };

    // ---- P0: gathered message, K = 512 ----
    if (P0) {
        for (int k0 = 0; k0 < HIDDEN; k0 += 32) {
            __syncthreads();
            {
                float sum[8];
                #pragma unroll
                for (int e = 0; e < 8; e++) sum[e] = 0.f;
                #pragma unroll
                for (int j = 0; j < MAX_NB; j++) {
                    s16x8 v = *reinterpret_cast<const s16x8*>(
                        msg + (size_t)sIdxA[r_st][j] * HIDDEN + k0 + s_st * 8);
                    #pragma unroll
                    for (int e = 0; e < 8; e++) sum[e] += uf((unsigned short)v[e]);
                }
                s16x8 o;
                #pragma unroll
                for (int e = 0; e < 8; e++) o[e] = (short)fb(sum[e]);
                *reinterpret_cast<s16x8*>(&As[r_st * LDSROW + s_st * 8]) = o;
            }
            stageB(Wm, k0 >> 5);
            __syncthreads();
            compute();
        }
    }
    // ---- P1: direct atom features, K = 160 (pad of 133) ----
    if (P1) {
        for (int k0 = 0; k0 < KA_PAD; k0 += 32) {
            __syncthreads();
            {
                int grow = m0 + r_st;
                s16x8 o;
                #pragma unroll
                for (int e = 0; e < 8; e++) {
                    int k = k0 + s_st * 8 + e;
                    float v = (grow < M && k < ATOM_FDIM)
                                  ? atomf[(size_t)grow * ATOM_FDIM + k] : 0.f;
                    o[e] = (short)fb(v);
                }
                *reinterpret_cast<s16x8*>(&As[r_st * LDSROW + s_st * 8]) = o;
            }
            stageB(Wa, k0 >> 5);
            __syncthreads();
            compute();
        }
    }
    // ---- P2: gathered bond features, K = 32 (pad of 14) ----
    if (P2) {
        __syncthreads();
        {
            float sum[8];
            #pragma unroll
            for (int e = 0; e < 8; e++) sum[e] = 0.f;
            #pragma unroll
            for (int j = 0; j < MAX_NB; j++) {
                size_t bbase = (size_t)sIdxB[r_st][j] * FB_DIM + ATOM_FDIM;
                #pragma unroll
                for (int e = 0; e < 8; e++) {
                    int k = s_st * 8 + e;
                    if (k < BOND_FDIM) sum[e] += fbonds[bbase + k];
                }
            }
            s16x8 o;
            #pragma unroll
            for (int e = 0; e < 8; e++) o[e] = (short)fb(sum[e]);
            *reinterpret_cast<s16x8*>(&As[r_st * LDSROW + s_st * 8]) = o;
        }
        stageB(Wb, 0);
        __syncthreads();
        compute();
    }

    // ---- epilogue ----
    #pragma unroll
    for (int mr = 0; mr < 4; mr++) {
        #pragma unroll
        for (int nr = 0; nr < 8; nr++) {
            int col = wn * 128 + nr * 16 + l15;
            #pragma unroll
            for (int rg = 0; rg < 4; rg++) {
                int row = m0 + mr * 16 + lhi * 4 + rg;
                if (row >= M) continue;
                size_t idx = (size_t)row * HIDDEN + col;
                float v = acc[mr][nr][rg];
                if (EPI == 0) {
                    outv[idx] = fb(fmaxf(v, 0.f));
                    if (baseOut) baseOut[idx] = fb(v + uf(baseOut[idx]));
                } else if (EPI == 1) {
                    outv[idx] = fb(fmaxf(v + uf(base[idx]), 0.f));
                } else {
                    outv[idx] = fb(fmaxf(v + bias[col], 0.f));
                }
            }
        }
    }
}

// ---------------------------------------------------------------------------
// flags[i] = (sum of atom_features row i) > 0.  One wave per row.
// ---------------------------------------------------------------------------
__global__ __launch_bounds__(256) void flags_k(const float* __restrict__ af,
                                               float* __restrict__ flags, int M)
{
    int w    = (blockIdx.x * 256 + threadIdx.x) >> 6;
    int lane = threadIdx.x & 63;
    if (w >= M) return;
    const float* row = af + (size_t)w * ATOM_FDIM;
    float s = 0.f;
    for (int c = lane; c < ATOM_FDIM; c += 64) s += row[c];
    #pragma unroll
    for (int off = 32; off; off >>= 1) s += __shfl_down(s, off);
    if (lane == 0) flags[w] = (s > 0.f) ? 1.f : 0.f;
}

// ---------------------------------------------------------------------------
// c_b[i] = (sum_j f_bonds[a2b[i][j]][133:147]) @ W_h[512:526] -> bf16
// ---------------------------------------------------------------------------
__global__ __launch_bounds__(256) void cb_k(const float* __restrict__ f_bonds,
                                            const int*   __restrict__ a2b,
                                            const float* __restrict__ Wh2,
                                            unsigned short* __restrict__ cb, int M)
{
    int atom = blockIdx.x * 4 + (threadIdx.x >> 6);
    int lane = threadIdx.x & 63;
    if (atom >= M) return;
    int bidx = (lane < MAX_NB) ? a2b[(size_t)atom * MAX_NB + lane] : 0;
    float nb = 0.f;
    if (lane < BOND_FDIM) {
        #pragma unroll
        for (int j = 0; j < MAX_NB; j++) {
            int b = __shfl(bidx, j);
            nb += f_bonds[(size_t)b * FB_DIM + ATOM_FDIM + lane];
        }
    }
    float acc[8];
    #pragma unroll
    for (int ci = 0; ci < 8; ci++) acc[ci] = 0.f;
    #pragma unroll
    for (int k = 0; k < BOND_FDIM; k++) {
        float nbk = __shfl(nb, k);
        #pragma unroll
        for (int ci = 0; ci < 8; ci++)
            acc[ci] += nbk * Wh2[(size_t)k * HIDDEN + lane + (ci << 6)];
    }
    size_t rb = (size_t)atom * HIDDEN;
    #pragma unroll
    for (int ci = 0; ci < 8; ci++) cb[rb + lane + (ci << 6)] = fb(acc[ci]);
}

// ---------------------------------------------------------------------------
// Per-molecule segment mean + counts; mol_ids sorted -> binary search bounds.
// ---------------------------------------------------------------------------
__global__ __launch_bounds__(512) void seg_k(const unsigned short* __restrict__ hid,
                                             const float* __restrict__ flags,
                                             const int*   __restrict__ mol_ids,
                                             float* __restrict__ out, int M, int NM)
{
    int m = blockIdx.x;
    int t = threadIdx.x;
    int lo = 0, hi = M;
    while (lo < hi) { int mid = (lo + hi) >> 1; if (mol_ids[mid] < m) lo = mid + 1; else hi = mid; }
    int s = lo;
    lo = 0; hi = M;
    while (lo < hi) { int mid = (lo + hi) >> 1; if (mol_ids[mid] < m + 1) lo = mid + 1; else hi = mid; }
    int e = lo;

    float acc = 0.f;
    for (int a = s; a < e; a++) acc += uf(hid[(size_t)a * HIDDEN + t]);
    float nzp = 0.f;
    for (int a = s + t; a < e; a += 512) nzp += flags[a];
    __shared__ float red[512];
    red[t] = nzp; __syncthreads();
    for (int off = 256; off; off >>= 1) { if (t < off) red[t] += red[t + off]; __syncthreads(); }

    int cnt = e - s;
    float inv = 1.f / fmaxf((float)cnt, 1.f);
    out[(size_t)m * HIDDEN + t] = acc * inv;
    if (t == 0) {
        out[(size_t)NM * HIDDEN + 2 * m]     = red[0];
        out[(size_t)NM * HIDDEN + 2 * m + 1] = (float)cnt;
    }
}

// ---------------------------------------------------------------------------
extern "C" void kernel_launch(void* const* d_in, const int* in_sizes, int n_in,
                              void* d_out, int out_size, void* d_ws, size_t ws_size,
                              hipStream_t stream)
{
    const float* atomf   = (const float*)d_in[0];
    const float* f_bonds = (const float*)d_in[1];
    const int*   a2a     = (const int*)d_in[2];
    const int*   a2b     = (const int*)d_in[3];
    const int*   mol_ids = (const int*)d_in[4];
    const float* W_i     = (const float*)d_in[5];
    const float* W_h     = (const float*)d_in[6];
    const float* W_o     = (const float*)d_in[7];
    const float* b_o     = (const float*)d_in[8];
    float* out = (float*)d_out;

    const int M  = in_sizes[2] / MAX_NB;   // 100000
    const int NM = 1000;
    const size_t SZ  = (size_t)M * HIDDEN;
    const size_t SZb = SZ * sizeof(unsigned short);

    const float* Wh2f = W_h + (size_t)HIDDEN * HIDDEN;

    // ---- workspace layout ----
    // bf16 tile-major weights: Wi(5 tiles) Wh1(16) Wh2(1) Wo1(5) Wo2(16)
    const size_t TCH = HIDDEN * 32;             // ushorts per tile (16384)
    unsigned short* Wt  = (unsigned short*)d_ws;
    unsigned short* WiT  = Wt;
    unsigned short* Wh1T = WiT  + 5  * TCH;
    unsigned short* Wh2T = Wh1T + 16 * TCH;
    unsigned short* Wo1T = Wh2T + 1  * TCH;
    unsigned short* Wo2T = Wo1T + 5  * TCH;
    unsigned short* wend = Wo2T + 16 * TCH;     // 43 tiles total
    float* flags = (float*)wend;
    char* p = (char*)(flags + M);
    const size_t fixed = (size_t)((char*)p - (char*)d_ws);

    const bool path3 = (ws_size >= fixed + 3 * SZb);
    unsigned short* baseB = nullptr;
    unsigned short *msgA, *msgB;
    if (path3) {
        baseB = (unsigned short*)p; p += SZb;
        msgA  = (unsigned short*)p; p += SZb;
        msgB  = (unsigned short*)p;
    } else {
        msgA  = (unsigned short*)p; p += SZb;
        msgB  = (unsigned short*)p;
    }

    const int gA = (M + 3) / 4;
    const int gG = (M + BM - 1) / BM;

    // ---- weight conversion ----
    cvt_w<<<(int)(5  * TCH / 8 + 255) / 256, 256, 0, stream>>>(W_i,  WiT,  ATOM_FDIM, 5  * 2048);
    cvt_w<<<(int)(16 * TCH / 8 + 255) / 256, 256, 0, stream>>>(W_h,  Wh1T, HIDDEN,    16 * 2048);
    cvt_w<<<(int)(1  * TCH / 8 + 255) / 256, 256, 0, stream>>>(Wh2f, Wh2T, BOND_FDIM, 1  * 2048);
    cvt_w<<<(int)(5  * TCH / 8 + 255) / 256, 256, 0, stream>>>(W_o,  Wo1T, ATOM_FDIM, 5  * 2048);
    cvt_w<<<(int)(16 * TCH / 8 + 255) / 256, 256, 0, stream>>>(W_o + (size_t)ATOM_FDIM * HIDDEN,
                                                               Wo2T, HIDDEN, 16 * 2048);
    flags_k<<<gA, 256, 0, stream>>>(atomf, flags, M);

    if (path3) {
        cb_k<<<gA, 256, 0, stream>>>(f_bonds, a2b, Wh2f, baseB, M);
        // msgA = relu(inp); baseB += inp
        mfma_gemm<0, false, true, false><<<gG, 256, 0, stream>>>(
            nullptr, nullptr, nullptr, atomf, WiT, nullptr, nullptr, nullptr,
            nullptr, nullptr, msgA, baseB, M);
        // 3 iters: msg' = relu(g6(msg)@Wh1 + base)
        mfma_gemm<1, true, false, false><<<gG, 256, 0, stream>>>(
            msgA, a2a, Wh1T, nullptr, nullptr, nullptr, nullptr, nullptr,
            baseB, nullptr, msgB, nullptr, M);
        mfma_gemm<1, true, false, false><<<gG, 256, 0, stream>>>(
            msgB, a2a, Wh1T, nullptr, nullptr, nullptr, nullptr, nullptr,
            baseB, nullptr, msgA, nullptr, M);
        mfma_gemm<1, true, false, false><<<gG, 256, 0, stream>>>(
            msgA, a2a, Wh1T, nullptr, nullptr, nullptr, nullptr, nullptr,
            baseB, nullptr, msgB, nullptr, M);
    } else {
        // msgA = relu(atomf @ W_i)
        mfma_gemm<0, false, true, false><<<gG, 256, 0, stream>>>(
            nullptr, nullptr, nullptr, atomf, WiT, nullptr, nullptr, nullptr,
            nullptr, nullptr, msgA, nullptr, M);
        // 3 iters: msg' = relu(g6(msg)@Wh1 + atomf@Wi + bond@Wh2)
        mfma_gemm<0, true, true, true><<<gG, 256, 0, stream>>>(
            msgA, a2a, Wh1T, atomf, WiT, f_bonds, a2b, Wh2T,
            nullptr, nullptr, msgB, nullptr, M);
        mfma_gemm<0, true, true, true><<<gG, 256, 0, stream>>>(
            msgB, a2a, Wh1T, atomf, WiT, f_bonds, a2b, Wh2T,
            nullptr, nullptr, msgA, nullptr, M);
        mfma_gemm<0, true, true, true><<<gG, 256, 0, stream>>>(
            msgA, a2a, Wh1T, atomf, WiT, f_bonds, a2b, Wh2T,
            nullptr, nullptr, msgB, nullptr, M);
    }
    // hid = relu(g6(msgB)@Wo2 + atomf@Wo1 + b_o) -> msgA
    mfma_gemm<2, true, true, false><<<gG, 256, 0, stream>>>(
        msgB, a2a, Wo2T, atomf, Wo1T, nullptr, nullptr, nullptr,
        nullptr, b_o, msgA, nullptr, M);
    // segment mean + counts
    seg_k<<<NM, 512, 0, stream>>>(msgA, flags, mol_ids, out, M, NM);
}

// Round 4
// 1496.513 us; speedup vs baseline: 5.5433x; 1.0259x over previous
//
#include <hip/hip_runtime.h>
#include <hip/hip_bf16.h>
#include <cstddef>

#define HIDDEN 512
#define ATOM_FDIM 133
#define BOND_FDIM 14
#define FB_DIM 147
#define MAX_NB 6
#define BM 64
#define AROW 40            // A LDS row pitch in ushorts (80 B => 2-way max)
#define KA_PAD 160         // atom K padded to 5 tiles of 32

typedef __attribute__((ext_vector_type(8))) short s16x8;
typedef __attribute__((ext_vector_type(4))) float f32x4;

__device__ __forceinline__ float uf(unsigned short u) {
    return __uint_as_float(((unsigned)u) << 16);
}
__device__ __forceinline__ unsigned short fb(float f) {
    __hip_bfloat16 h = __float2bfloat16(f);
    return *reinterpret_cast<unsigned short*>(&h);
}

// ---------------------------------------------------------------------------
// One-time weight convert: f32 [Ksrc][512] -> bf16 tile-major with k-octet
// slot swizzle. Physical chunk c (16 B): tile=c>>11, n=(c&2047)>>2, sp=c&3;
// logical k-octet s = sp ^ ((n>>1)&3). Chunk holds W[tile*32+s*8+e][n].
// Reader applies the same XOR -> bank-conflict-free ds_read_b128.
// ---------------------------------------------------------------------------
__global__ __launch_bounds__(256) void cvt_w(const float* __restrict__ src,
                                             unsigned short* __restrict__ dst,
                                             int Ksrc, int nchunks)
{
    int c = blockIdx.x * 256 + threadIdx.x;
    if (c >= nchunks) return;
    int tile = c >> 11, pc = c & 2047, n = pc >> 2, sp = pc & 3;
    int s = sp ^ ((n >> 1) & 3);
    s16x8 o;
    #pragma unroll
    for (int e = 0; e < 8; e++) {
        int k = tile * 32 + s * 8 + e;
        float v = (k < Ksrc) ? src[(size_t)k * HIDDEN + n] : 0.f;
        o[e] = (short)fb(v);
    }
    reinterpret_cast<s16x8*>(dst)[c] = o;
}

// ---------------------------------------------------------------------------
// MFMA multi-phase GEMM. 256 thr = 4 waves, BM=64 x BN=512, BK=32.
// Wave wn covers cols [wn*128, +128): 4 M-frags x 8 N-frags.
// P0 (msg gather, K=512): software-pipelined, double-buffered LDS:
//   issue loads(t+1) -> compute(t) -> drain+write LDS(t+1) -> barrier.
// P1 (atomf, K=160 pad 133), P2 (bond gather, K=32 pad 14): simple loop.
// ---------------------------------------------------------------------------
template<int EPI, bool P0, bool P1, bool P2>
__global__ __launch_bounds__(256, 2) void mfma_gemm(
    const unsigned short* __restrict__ msg, const int* __restrict__ a2a,
    const unsigned short* __restrict__ Wm,
    const float* __restrict__ atomf, const unsigned short* __restrict__ Wa,
    const float* __restrict__ fbonds, const int* __restrict__ a2b,
    const unsigned short* __restrict__ Wb,
    const unsigned short* __restrict__ base, const float* __restrict__ bias,
    unsigned short* __restrict__ outv, unsigned short* __restrict__ baseOut,
    int M)
{
    __shared__ unsigned short As[2][BM * AROW];      // 10 KB
    __shared__ unsigned short Bs[2][HIDDEN * 32];    // 64 KB (swizzled phys)
    __shared__ int sIdxB[BM][MAX_NB];

    const int t    = threadIdx.x;
    const int m0   = blockIdx.x * BM;
    const int lane = t & 63;
    const int l15  = lane & 15, lhi = lane >> 4;
    const int wn   = t >> 6;
    const int r_st = t >> 2, s_st = t & 3;           // staging coords

    // neighbor indices for this thread's staging row, in registers
    int aidx[MAX_NB];
    if (P0) {
        int row = m0 + r_st; if (row >= M) row = M - 1;
        #pragma unroll
        for (int j = 0; j < MAX_NB; j++) aidx[j] = a2a[(size_t)row * MAX_NB + j];
    }
    if (P2) {
        for (int e = t; e < BM * MAX_NB; e += 256) {
            int r = e / MAX_NB, j = e % MAX_NB;
            int row = m0 + r; if (row >= M) row = M - 1;
            sIdxB[r][j] = a2b[(size_t)row * MAX_NB + j];
        }
    }

    f32x4 acc[4][8];
    #pragma unroll
    for (int mr = 0; mr < 4; mr++)
        #pragma unroll
        for (int nr = 0; nr < 8; nr++)
            acc[mr][nr] = (f32x4){0.f, 0.f, 0.f, 0.f};

    s16x8 aPre[MAX_NB];
    s16x8 bPre[8];

    auto issueA = [&](int k0) {
        #pragma unroll
        for (int j = 0; j < MAX_NB; j++)
            aPre[j] = *reinterpret_cast<const s16x8*>(
                msg + (size_t)aidx[j] * HIDDEN + k0 + s_st * 8);
    };
    auto issueB = [&](const unsigned short* Wt, int tile) {
        const s16x8* src = reinterpret_cast<const s16x8*>(Wt + (size_t)tile * (HIDDEN * 32));
        #pragma unroll
        for (int i = 0; i < 8; i++) bPre[i] = src[t + i * 256];
    };
    auto writeA = [&](int buf) {
        float sum[8];
        #pragma unroll
        for (int e = 0; e < 8; e++) sum[e] = 0.f;
        #pragma unroll
        for (int j = 0; j < MAX_NB; j++)
            #pragma unroll
            for (int e = 0; e < 8; e++) sum[e] += uf((unsigned short)aPre[j][e]);
        s16x8 o;
        #pragma unroll
        for (int e = 0; e < 8; e++) o[e] = (short)fb(sum[e]);
        *reinterpret_cast<s16x8*>(&As[buf][r_st * AROW + s_st * 8]) = o;
    };
    auto writeB = [&](int buf) {
        s16x8* dst = reinterpret_cast<s16x8*>(&Bs[buf][0]);
        #pragma unroll
        for (int i = 0; i < 8; i++) dst[t + i * 256] = bPre[i];
    };
    auto compute = [&](int buf) {
        const unsigned short* Ab = &As[buf][0];
        const unsigned short* Bb = &Bs[buf][0];
        s16x8 af[4];
        #pragma unroll
        for (int mr = 0; mr < 4; mr++)
            af[mr] = *reinterpret_cast<const s16x8*>(&Ab[(mr * 16 + l15) * AROW + lhi * 8]);
        const int slot = lhi ^ ((l15 >> 1) & 3);
        const unsigned short* bb = &Bb[(wn * 128 + l15) * 32 + slot * 8];
        #pragma unroll
        for (int nr = 0; nr < 8; nr++) {
            s16x8 bf = *reinterpret_cast<const s16x8*>(bb + nr * 512);
            #pragma unroll
            for (int mr = 0; mr < 4; mr++)
                acc[mr][nr] = __builtin_amdgcn_mfma_f32_16x16x32_bf16(af[mr], bf, acc[mr][nr], 0, 0, 0);
        }
    };

    // ---- P0: gathered message, K = 512, pipelined ----
    if (P0) {
        issueA(0); issueB(Wm, 0);
        writeA(0); writeB(0);
        __syncthreads();
        for (int tile = 0; tile < 15; ++tile) {
            int cur = tile & 1;
            issueA((tile + 1) * 32);
            issueB(Wm, tile + 1);
            __builtin_amdgcn_sched_barrier(0);
            compute(cur);
            writeA(cur ^ 1); writeB(cur ^ 1);
            __syncthreads();
        }
        compute(1);
        __syncthreads();
    }
    // ---- P1: direct atom features, K = 160 (pad of 133) ----
    if (P1) {
        for (int tile = 0; tile < KA_PAD / 32; ++tile) {
            int grow = m0 + r_st;
            s16x8 o;
            #pragma unroll
            for (int e = 0; e < 8; e++) {
                int k = tile * 32 + s_st * 8 + e;
                float v = (grow < M && k < ATOM_FDIM)
                              ? atomf[(size_t)grow * ATOM_FDIM + k] : 0.f;
                o[e] = (short)fb(v);
            }
            *reinterpret_cast<s16x8*>(&As[0][r_st * AROW + s_st * 8]) = o;
            issueB(Wa, tile); writeB(0);
            __syncthreads();
            compute(0);
            __syncthreads();
        }
    }
    // ---- P2: gathered bond features, K = 32 (pad of 14) ----
    if (P2) {
        {
            float sum[8];
            #pragma unroll
            for (int e = 0; e < 8; e++) sum[e] = 0.f;
            #pragma unroll
            for (int j = 0; j < MAX_NB; j++) {
                size_t bbase = (size_t)sIdxB[r_st][j] * FB_DIM + ATOM_FDIM;
                #pragma unroll
                for (int e = 0; e < 8; e++) {
                    int k = s_st * 8 + e;
                    if (k < BOND_FDIM) sum[e] += fbonds[bbase + k];
                }
            }
            s16x8 o;
            #pragma unroll
            for (int e = 0; e < 8; e++) o[e] = (short)fb(sum[e]);
            *reinterpret_cast<s16x8*>(&As[0][r_st * AROW + s_st * 8]) = o;
        }
        issueB(Wb, 0); writeB(0);
        __syncthreads();
        compute(0);
    }

    // ---- epilogue ----
    #pragma unroll
    for (int mr = 0; mr < 4; mr++) {
        #pragma unroll
        for (int nr = 0; nr < 8; nr++) {
            int col = wn * 128 + nr * 16 + l15;
            #pragma unroll
            for (int rg = 0; rg < 4; rg++) {
                int row = m0 + mr * 16 + lhi * 4 + rg;
                if (row >= M) continue;
                size_t idx = (size_t)row * HIDDEN + col;
                float v = acc[mr][nr][rg];
                if (EPI == 0) {
                    outv[idx] = fb(fmaxf(v, 0.f));
                    if (baseOut) baseOut[idx] = fb(v + uf(baseOut[idx]));
                } else if (EPI == 1) {
                    outv[idx] = fb(fmaxf(v + uf(base[idx]), 0.f));
                } else {
                    outv[idx] = fb(fmaxf(v + bias[col], 0.f));
                }
            }
        }
    }
}

// ---------------------------------------------------------------------------
// flags[i] = (sum of atom_features row i) > 0.  One wave per row.
// ---------------------------------------------------------------------------
__global__ __launch_bounds__(256) void flags_k(const float* __restrict__ af,
                                               float* __restrict__ flags, int M)
{
    int w    = (blockIdx.x * 256 + threadIdx.x) >> 6;
    int lane = threadIdx.x & 63;
    if (w >= M) return;
    const float* row = af + (size_t)w * ATOM_FDIM;
    float s = 0.f;
    for (int c = lane; c < ATOM_FDIM; c += 64) s += row[c];
    #pragma unroll
    for (int off = 32; off; off >>= 1) s += __shfl_down(s, off);
    if (lane == 0) flags[w] = (s > 0.f) ? 1.f : 0.f;
}

// ---------------------------------------------------------------------------
// c_b[i] = (sum_j f_bonds[a2b[i][j]][133:147]) @ W_h[512:526] -> bf16
// ---------------------------------------------------------------------------
__global__ __launch_bounds__(256) void cb_k(const float* __restrict__ f_bonds,
                                            const int*   __restrict__ a2b,
                                            const float* __restrict__ Wh2,
                                            unsigned short* __restrict__ cb, int M)
{
    int atom = blockIdx.x * 4 + (threadIdx.x >> 6);
    int lane = threadIdx.x & 63;
    if (atom >= M) return;
    int bidx = (lane < MAX_NB) ? a2b[(size_t)atom * MAX_NB + lane] : 0;
    float nb = 0.f;
    if (lane < BOND_FDIM) {
        #pragma unroll
        for (int j = 0; j < MAX_NB; j++) {
            int b = __shfl(bidx, j);
            nb += f_bonds[(size_t)b * FB_DIM + ATOM_FDIM + lane];
        }
    }
    float acc[8];
    #pragma unroll
    for (int ci = 0; ci < 8; ci++) acc[ci] = 0.f;
    #pragma unroll
    for (int k = 0; k < BOND_FDIM; k++) {
        float nbk = __shfl(nb, k);
        #pragma unroll
        for (int ci = 0; ci < 8; ci++)
            acc[ci] += nbk * Wh2[(size_t)k * HIDDEN + lane + (ci << 6)];
    }
    size_t rb = (size_t)atom * HIDDEN;
    #pragma unroll
    for (int ci = 0; ci < 8; ci++) cb[rb + lane + (ci << 6)] = fb(acc[ci]);
}

// ---------------------------------------------------------------------------
// Per-molecule segment mean + counts; mol_ids sorted -> binary search bounds.
// ---------------------------------------------------------------------------
__global__ __launch_bounds__(512) void seg_k(const unsigned short* __restrict__ hid,
                                             const float* __restrict__ flags,
                                             const int*   __restrict__ mol_ids,
                                             float* __restrict__ out, int M, int NM)
{
    int m = blockIdx.x;
    int t = threadIdx.x;
    int lo = 0, hi = M;
    while (lo < hi) { int mid = (lo + hi) >> 1; if (mol_ids[mid] < m) lo = mid + 1; else hi = mid; }
    int s = lo;
    lo = 0; hi = M;
    while (lo < hi) { int mid = (lo + hi) >> 1; if (mol_ids[mid] < m + 1) lo = mid + 1; else hi = mid; }
    int e = lo;

    float acc = 0.f;
    for (int a = s; a < e; a++) acc += uf(hid[(size_t)a * HIDDEN + t]);
    float nzp = 0.f;
    for (int a = s + t; a < e; a += 512) nzp += flags[a];
    __shared__ float red[512];
    red[t] = nzp; __syncthreads();
    for (int off = 256; off; off >>= 1) { if (t < off) red[t] += red[t + off]; __syncthreads(); }

    int cnt = e - s;
    float inv = 1.f / fmaxf((float)cnt, 1.f);
    out[(size_t)m * HIDDEN + t] = acc * inv;
    if (t == 0) {
        out[(size_t)NM * HIDDEN + 2 * m]     = red[0];
        out[(size_t)NM * HIDDEN + 2 * m + 1] = (float)cnt;
    }
}

// ---------------------------------------------------------------------------
extern "C" void kernel_launch(void* const* d_in, const int* in_sizes, int n_in,
                              void* d_out, int out_size, void* d_ws, size_t ws_size,
                              hipStream_t stream)
{
    const float* atomf   = (const float*)d_in[0];
    const float* f_bonds = (const float*)d_in[1];
    const int*   a2a     = (const int*)d_in[2];
    const int*   a2b     = (const int*)d_in[3];
    const int*   mol_ids = (const int*)d_in[4];
    const float* W_i     = (const float*)d_in[5];
    const float* W_h     = (const float*)d_in[6];
    const float* W_o     = (const float*)d_in[7];
    const float* b_o     = (const float*)d_in[8];
    float* out = (float*)d_out;

    const int M  = in_sizes[2] / MAX_NB;   // 100000
    const int NM = 1000;
    const size_t SZ  = (size_t)M * HIDDEN;
    const size_t SZb = SZ * sizeof(unsigned short);

    const float* Wh2f = W_h + (size_t)HIDDEN * HIDDEN;

    // ---- workspace layout ----
    const size_t TCH = HIDDEN * 32;             // ushorts per tile (16384)
    unsigned short* WiT  = (unsigned short*)d_ws;
    unsigned short* Wh1T = WiT  + 5  * TCH;
    unsigned short* Wh2T = Wh1T + 16 * TCH;
    unsigned short* Wo1T = Wh2T + 1  * TCH;
    unsigned short* Wo2T = Wo1T + 5  * TCH;
    unsigned short* wend = Wo2T + 16 * TCH;     // 43 tiles total
    float* flags = (float*)wend;
    char* p = (char*)(flags + M);
    const size_t fixed = (size_t)((char*)p - (char*)d_ws);

    const bool path3 = (ws_size >= fixed + 3 * SZb);
    unsigned short* baseB = nullptr;
    unsigned short *msgA, *msgB;
    if (path3) {
        baseB = (unsigned short*)p; p += SZb;
        msgA  = (unsigned short*)p; p += SZb;
        msgB  = (unsigned short*)p;
    } else {
        msgA  = (unsigned short*)p; p += SZb;
        msgB  = (unsigned short*)p;
    }

    const int gA = (M + 3) / 4;
    const int gG = (M + BM - 1) / BM;

    // ---- weight conversion (swizzled bf16 tiles) ----
    cvt_w<<<(5  * 2048 + 255) / 256, 256, 0, stream>>>(W_i,  WiT,  ATOM_FDIM, 5  * 2048);
    cvt_w<<<(16 * 2048 + 255) / 256, 256, 0, stream>>>(W_h,  Wh1T, HIDDEN,    16 * 2048);
    cvt_w<<<(1  * 2048 + 255) / 256, 256, 0, stream>>>(Wh2f, Wh2T, BOND_FDIM, 1  * 2048);
    cvt_w<<<(5  * 2048 + 255) / 256, 256, 0, stream>>>(W_o,  Wo1T, ATOM_FDIM, 5  * 2048);
    cvt_w<<<(16 * 2048 + 255) / 256, 256, 0, stream>>>(W_o + (size_t)ATOM_FDIM * HIDDEN,
                                                       Wo2T, HIDDEN, 16 * 2048);
    flags_k<<<gA, 256, 0, stream>>>(atomf, flags, M);

    if (path3) {
        cb_k<<<gA, 256, 0, stream>>>(f_bonds, a2b, Wh2f, baseB, M);
        // msgA = relu(inp); baseB += inp
        mfma_gemm<0, false, true, false><<<gG, 256, 0, stream>>>(
            nullptr, nullptr, nullptr, atomf, WiT, nullptr, nullptr, nullptr,
            nullptr, nullptr, msgA, baseB, M);
        // 3 iters: msg' = relu(g6(msg)@Wh1 + base)
        mfma_gemm<1, true, false, false><<<gG, 256, 0, stream>>>(
            msgA, a2a, Wh1T, nullptr, nullptr, nullptr, nullptr, nullptr,
            baseB, nullptr, msgB, nullptr, M);
        mfma_gemm<1, true, false, false><<<gG, 256, 0, stream>>>(
            msgB, a2a, Wh1T, nullptr, nullptr, nullptr, nullptr, nullptr,
            baseB, nullptr, msgA, nullptr, M);
        mfma_gemm<1, true, false, false><<<gG, 256, 0, stream>>>(
            msgA, a2a, Wh1T, nullptr, nullptr, nullptr, nullptr, nullptr,
            baseB, nullptr, msgB, nullptr, M);
    } else {
        mfma_gemm<0, false, true, false><<<gG, 256, 0, stream>>>(
            nullptr, nullptr, nullptr, atomf, WiT, nullptr, nullptr, nullptr,
            nullptr, nullptr, msgA, nullptr, M);
        mfma_gemm<0, true, true, true><<<gG, 256, 0, stream>>>(
            msgA, a2a, Wh1T, atomf, WiT, f_bonds, a2b, Wh2T,
            nullptr, nullptr, msgB, nullptr, M);
        mfma_gemm<0, true, true, true><<<gG, 256, 0, stream>>>(
            msgB, a2a, Wh1T, atomf, WiT, f_bonds, a2b, Wh2T,
            nullptr, nullptr, msgA, nullptr, M);
        mfma_gemm<0, true, true, true><<<gG, 256, 0, stream>>>(
            msgA, a2a, Wh1T, atomf, WiT, f_bonds, a2b, Wh2T,
            nullptr, nullptr, msgB, nullptr, M);
    }
    // hid = relu(g6(msgB)@Wo2 + atomf@Wo1 + b_o) -> msgA
    mfma_gemm<2, true, true, false><<<gG, 256, 0, stream>>>(
        msgB, a2a, Wo2T, atomf, Wo1T, nullptr, nullptr, nullptr,
        nullptr, b_o, msgA, nullptr, M);
    // segment mean + counts
    seg_k<<<NM, 512, 0, stream>>>(msgA, flags, mol_ids, out, M, NM);
}